// Round 3
// baseline (448.254 us; speedup 1.0000x reference)
//
#include <hip/hip_runtime.h>
#include <math.h>

#define NB 8
#define NN 2048
#define ND 128
#define NHID 256
#define PROJ 64
#define TH_IN 387
#define TH_HID 128

// ---------------- Kernel A: seed/argmax, kq = Wk^T (Wq @ x_seed), theta MLP ----
// 1024 threads (16 waves) per block, one block per batch. Also zeroes the
// per-batch completion counters used by the fused row+trim kernel (must be
// re-zeroed every launch for graph-replay determinism).
__global__ __launch_bounds__(1024) void seed_theta_kernel(
    const float* __restrict__ x, const float* __restrict__ seed_ctx,
    const float* __restrict__ local_stats, const float* __restrict__ cmask,
    const float* __restrict__ Wq, const float* __restrict__ Wk,
    const float* __restrict__ W1, const float* __restrict__ b1,
    const float* __restrict__ W2, const float* __restrict__ b2,
    float* __restrict__ kq_ws, float* __restrict__ theta_ws,
    int* __restrict__ counters, float* __restrict__ out_theta)
{
  const int b = blockIdx.x;
  const int t = threadIdx.x;
  const int wave = t >> 6, lane = t & 63;

  __shared__ float swv[16]; __shared__ int swi[16];
  __shared__ float sx[ND];
  __shared__ float sq[PROJ];
  __shared__ float tin[TH_IN];
  __shared__ float part[8][TH_HID];
  __shared__ float sred[TH_HID];
  __shared__ int s_seed;

  if (t == 0) counters[b] = 0;   // reset fused-kernel counter every launch

  // ---- argmax(cluster_mask[b]) -> earliest index attaining max ----
  {
    float v0 = cmask[b*NN + t];
    float v1 = cmask[b*NN + t + 1024];
    float bv = v0; int bi = t;
    if (v1 > bv) { bv = v1; bi = t + 1024; }
    // wave-level (value,index) reduce, lowest index wins ties
    for (int off = 32; off; off >>= 1) {
      float ov = __shfl_xor(bv, off);
      int   oi = __shfl_xor(bi, off);
      if (ov > bv || (ov == bv && oi < bi)) { bv = ov; bi = oi; }
    }
    if (lane == 0) { swv[wave] = bv; swi[wave] = bi; }
  }
  __syncthreads();
  if (t == 0) {
    float bv = swv[0]; int bi = swi[0];
    #pragma unroll
    for (int w = 1; w < 16; ++w) {
      if (swv[w] > bv || (swv[w] == bv && swi[w] < bi)) { bv = swv[w]; bi = swi[w]; }
    }
    s_seed = bi;
  }
  __syncthreads();
  const int seed = s_seed;

  if (t < ND) sx[t] = x[((size_t)b*NN + seed)*ND + t];
  __syncthreads();

  // ---- q[h] = Wq[h,:] . sx  — one h per (wave, j), lane-split + shfl reduce
  {
    const int h = wave*4;
    #pragma unroll
    for (int j = 0; j < 4; ++j) {
      float a = Wq[(h+j)*ND + lane] * sx[lane]
              + Wq[(h+j)*ND + 64 + lane] * sx[64 + lane];
      for (int off = 32; off; off >>= 1) a += __shfl_xor(a, off);
      if (lane == 0) sq[h+j] = a;
    }
  }
  __syncthreads();

  // ---- kq[d] = sum_h Wk[h,d]*q[h] — split h into 8 chunks across threads
  {
    const int c = t >> 7;            // 0..7
    const int d = t & 127;
    float acc = 0.f;
    #pragma unroll
    for (int j = 0; j < 8; ++j) acc += Wk[(c*8 + j)*ND + d] * sq[c*8 + j];
    part[c][d] = acc;
  }
  __syncthreads();
  if (t < ND) {
    float acc = 0.f;
    #pragma unroll
    for (int c = 0; c < 8; ++c) acc += part[c][t];
    kq_ws[b*ND + t] = acc;
  }

  // ---- theta head: h = Linear(387->128) -> ReLU -> Linear(128->1)
  if (t < ND + NHID) tin[t] = seed_ctx[b*(ND+NHID) + t];
  if (t >= ND + NHID && t < TH_IN) tin[t] = local_stats[b*3 + (t - (ND+NHID))];
  __syncthreads();
  {
    const int c = t >> 7;            // i-chunk 0..7, ~49 each
    const int h = t & 127;
    const int i0 = c*49;
    const int i1 = (c == 7) ? TH_IN : i0 + 49;
    float acc = 0.f;
    for (int i = i0; i < i1; ++i) acc += tin[i] * W1[i*TH_HID + h];
    part[c][h] = acc;
  }
  __syncthreads();
  if (t < TH_HID) {
    float acc = b1[t];
    #pragma unroll
    for (int c = 0; c < 8; ++c) acc += part[c][t];
    acc = fmaxf(acc, 0.f);
    sred[t] = acc * W2[t];
  }
  __syncthreads();
  if (t < 64) {
    float v = sred[t] + sred[t + 64];
    for (int off = 32; off; off >>= 1) v += __shfl_xor(v, off);
    if (t == 0) {
      float th = v + b2[0];
      theta_ws[b] = th;
      out_theta[b] = th;
    }
  }
}

// ------- Kernel B: one wave per adj row + last-block-per-batch trim ----------
__global__ __launch_bounds__(256) void row_trim_kernel(
    const float* __restrict__ x, const float* __restrict__ adj,
    const float* __restrict__ cmask, const float* __restrict__ candm,
    const float* __restrict__ kq_ws, const float* __restrict__ theta_ws,
    int* __restrict__ counters,
    float* __restrict__ out_hard, float* __restrict__ out_p)
{
  const int t = threadIdx.x;
  const int wave = t >> 6, lane = t & 63;
  const int row0 = blockIdx.x * 4;
  const int b = row0 >> 11;               // 2048 rows per batch, 4 rows/block
  __shared__ float sCm[NN];
  __shared__ float sKq[ND];
  __shared__ float sTheta;
  __shared__ int s_prev;

  const float4* cm4 = (const float4*)(cmask + b*NN);
  float4* sCm4 = (float4*)sCm;
  for (int i = t; i < NN/4; i += 256) sCm4[i] = cm4[i];
  if (t < ND) sKq[t] = kq_ws[b*ND + t];
  if (t == 0) sTheta = theta_ws[b];
  __syncthreads();

  const int row = row0 + wave;            // == b*NN + n
  const float4* a4 = (const float4*)(adj + (size_t)row * NN);
  float deg = 0.f, e2c = 0.f;
  #pragma unroll
  for (int k = 0; k < 8; ++k) {
    const int idx = k*64 + lane;
    float4 a = a4[idx];
    float4 c = sCm4[idx];
    deg += a.x + a.y + a.z + a.w;
    e2c += a.x*c.x + a.y*c.y + a.z*c.z + a.w*c.w;
  }
  const float2* x2 = (const float2*)(x + ((size_t)row)*ND);
  float2 xv = x2[lane];
  float sc = xv.x * sKq[2*lane] + xv.y * sKq[2*lane + 1];

  for (int off = 32; off; off >>= 1) {
    deg += __shfl_xor(deg, off);
    e2c += __shfl_xor(e2c, off);
    sc  += __shfl_xor(sc, off);
  }

  if (lane == 0) {
    float dd = fmaxf(deg, 1.0f);
    float cand = sc * 0.125f + 0.2f * (e2c / dd);   // /sqrt(64) == *0.125 exact
    float logit = cand - sTheta;                    // TAU == 1
    float p = 1.0f / (1.0f + expf(-logit));
    p *= candm[row];
    out_p[row] = p;
    out_hard[row] = (p > 0.5f) ? 1.0f : 0.0f;
    __threadfence();                    // make this wave's p/hard device-visible
  }
  __syncthreads();
  if (t == 0) s_prev = atomicAdd(&counters[b], 1);
  __syncthreads();
  if (s_prev != 511) return;            // not the last block of this batch

  // ---- last block of batch b: count + stable top-2 + trim (reads are L2-hot)
  __threadfence();                      // acquire: see all 512 blocks' writes
  float* p    = out_p    + b*NN;
  float* hard = out_hard + b*NN;
  __shared__ int scnt[256];
  __shared__ float sv1[256]; __shared__ int si1[256];
  __shared__ float sv2[256]; __shared__ int si2[256];
  __shared__ int s_trim, s_k1, s_k2;

  int cnt = 0;
  float v1 = -1e30f, v2 = -1e30f; int i1 = 0, i2 = 0;
  const int base = t*8;                 // contiguous chunk: thread order == index order
  #pragma unroll
  for (int j = 0; j < 8; ++j) {
    const int nidx = base + j;
    const float v = p[nidx];
    if (v > 0.5f) ++cnt;
    if (v > v1)      { v2 = v1; i2 = i1; v1 = v; i1 = nidx; }
    else if (v > v2) { v2 = v;  i2 = nidx; }
  }
  scnt[t] = cnt; sv1[t]=v1; si1[t]=i1; sv2[t]=v2; si2[t]=i2;
  __syncthreads();
  // tree-merge: t's set covers strictly lower indices than t+s's, so strict '>'
  // comparisons preserve lax.top_k's lowest-index tie-break.
  for (int s = 128; s > 0; s >>= 1) {
    if (t < s) {
      scnt[t] += scnt[t+s];
      float B1 = sv1[t+s]; int Bi1 = si1[t+s];
      float B2 = sv2[t+s]; int Bi2 = si2[t+s];
      float V1 = sv1[t], V2 = sv2[t]; int I1 = si1[t], I2 = si2[t];
      if (B1 > V1)      { V2=V1; I2=I1; V1=B1; I1=Bi1; }
      else if (B1 > V2) { V2=B1; I2=Bi1; }
      if (B2 > V1)      { V2=V1; I2=I1; V1=B2; I1=Bi2; }
      else if (B2 > V2) { V2=B2; I2=Bi2; }
      sv1[t]=V1; si1[t]=I1; sv2[t]=V2; si2[t]=I2;
    }
    __syncthreads();
  }
  if (t == 0) {
    s_trim = (scnt[0] > 2) ? 1 : 0;     // over = count - (CLUSTER_SIZE_MAX-1) > 0
    s_k1 = si1[0]; s_k2 = si2[0];
  }
  __syncthreads();
  if (s_trim) {
    for (int nidx = t; nidx < NN; nidx += 256) {
      if (nidx != s_k1 && nidx != s_k2) { p[nidx] = 0.f; hard[nidx] = 0.f; }
    }
  }
}

extern "C" void kernel_launch(void* const* d_in, const int* in_sizes, int n_in,
                              void* d_out, int out_size, void* d_ws, size_t ws_size,
                              hipStream_t stream) {
  const float* x          = (const float*)d_in[0];
  const float* adj        = (const float*)d_in[1];
  const float* seed_ctx   = (const float*)d_in[2];
  const float* local_st   = (const float*)d_in[3];
  const float* cmask      = (const float*)d_in[4];
  const float* candm      = (const float*)d_in[5];
  const float* Wq         = (const float*)d_in[6];
  const float* Wk         = (const float*)d_in[7];
  const float* W1         = (const float*)d_in[8];
  const float* b1         = (const float*)d_in[9];
  const float* W2         = (const float*)d_in[10];
  const float* b2         = (const float*)d_in[11];

  float* out      = (float*)d_out;
  float* out_hard = out;                // [B,N]
  float* out_p    = out + NB*NN;        // [B,N]
  float* out_th   = out + 2*NB*NN;      // [B]

  float* ws       = (float*)d_ws;
  float* kq_ws    = ws;                 // B*D floats
  float* theta_ws = ws + NB*ND;         // B floats
  int*   counters = (int*)(ws + NB*ND + NB);   // B ints

  seed_theta_kernel<<<NB, 1024, 0, stream>>>(x, seed_ctx, local_st, cmask,
                                             Wq, Wk, W1, b1, W2, b2,
                                             kq_ws, theta_ws, counters, out_th);
  row_trim_kernel<<<(NB*NN)/4, 256, 0, stream>>>(x, adj, cmask, candm,
                                                 kq_ws, theta_ws, counters,
                                                 out_hard, out_p);
}

// Round 4
// 54.337 us; speedup vs baseline: 8.2496x; 8.2496x over previous
//
#include <hip/hip_runtime.h>
#include <math.h>

#define NB 8
#define NN 2048
#define ND 128
#define NHID 256
#define PROJ 64
#define TH_IN 387
#define TH_HID 128

// ---- Kernel B: 8 adj rows per block + per-block redundant kq; writes cand ----
// No dependency on any other kernel. 2048 blocks x 512 threads (8 waves).
__global__ __launch_bounds__(512) void row_cand_kernel(
    const float* __restrict__ x, const float* __restrict__ adj,
    const float* __restrict__ cmask,
    const float* __restrict__ Wq, const float* __restrict__ Wk,
    float* __restrict__ cand_ws)
{
  const int t = threadIdx.x;
  const int wave = t >> 6, lane = t & 63;
  const int bb = blockIdx.x >> 8;          // batch (256 blocks per batch)
  const int r0 = (blockIdx.x & 255) * 8;   // first row of this block

  __shared__ float sCm[NN];                // 8 KB
  __shared__ float sx[ND];
  __shared__ float sq[PROJ];
  __shared__ float qp[8][PROJ];
  __shared__ float kp[4][ND];
  __shared__ float sKq[ND];
  __shared__ float swv[8]; __shared__ int swi[8];
  __shared__ int s_seed;

  // ---- stage cluster mask (one float4 per thread) ----
  const float4* cm4 = (const float4*)(cmask + bb*NN);
  ((float4*)sCm)[t] = cm4[t];
  __syncthreads();

  // ---- argmax(cmask) -> earliest index attaining max ----
  {
    float bv = sCm[t]; int bi = t;          // ascending order => strict '>' keeps lowest
    float v1 = sCm[t+512];  if (v1 > bv) { bv = v1; bi = t+512; }
    float v2 = sCm[t+1024]; if (v2 > bv) { bv = v2; bi = t+1024; }
    float v3 = sCm[t+1536]; if (v3 > bv) { bv = v3; bi = t+1536; }
    for (int off = 32; off; off >>= 1) {
      float ov = __shfl_xor(bv, off);
      int   oi = __shfl_xor(bi, off);
      if (ov > bv || (ov == bv && oi < bi)) { bv = ov; bi = oi; }
    }
    if (lane == 0) { swv[wave] = bv; swi[wave] = bi; }
  }
  __syncthreads();
  if (t == 0) {
    float bv = swv[0]; int bi = swi[0];
    #pragma unroll
    for (int w = 1; w < 8; ++w)
      if (swv[w] > bv || (swv[w] == bv && swi[w] < bi)) { bv = swv[w]; bi = swi[w]; }
    s_seed = bi;
  }
  __syncthreads();
  if (t < ND) sx[t] = x[((size_t)bb*NN + s_seed)*ND + t];
  __syncthreads();

  // ---- q[h] = Wq[h,:]·x_seed : h = t&63, 8 d-chunks of 16 ----
  {
    const int h = t & 63, pp = t >> 6;
    float a = 0.f;
    #pragma unroll
    for (int j = 0; j < 16; ++j) a += Wq[h*ND + pp*16 + j] * sx[pp*16 + j];
    qp[pp][h] = a;
  }
  __syncthreads();
  if (t < PROJ) {
    float a = 0.f;
    #pragma unroll
    for (int pp = 0; pp < 8; ++pp) a += qp[pp][t];
    sq[t] = a;
  }
  __syncthreads();

  // ---- kq[d] = sum_h Wk[h,d]*q[h] : d = t&127, 4 h-chunks of 16 (coalesced) --
  {
    const int d = t & 127, hc = t >> 7;
    float a = 0.f;
    #pragma unroll
    for (int j = 0; j < 16; ++j) a += Wk[(hc*16 + j)*ND + d] * sq[hc*16 + j];
    kp[hc][d] = a;
  }
  __syncthreads();
  if (t < ND) sKq[t] = kp[0][t] + kp[1][t] + kp[2][t] + kp[3][t];
  __syncthreads();

  // ---- stream one adj row per wave: deg, e2c, score -> cand ----
  const int grow = bb*NN + r0 + wave;
  const float4* a4 = (const float4*)(adj + (size_t)grow * NN);
  float deg = 0.f, e2c = 0.f;
  #pragma unroll
  for (int k = 0; k < 8; ++k) {
    const int idx = k*64 + lane;
    float4 a = a4[idx];
    float4 c = ((float4*)sCm)[idx];
    deg += a.x + a.y + a.z + a.w;
    e2c += a.x*c.x + a.y*c.y + a.z*c.z + a.w*c.w;
  }
  const float2* x2 = (const float2*)(x + (size_t)grow * ND);
  float2 xv = x2[lane];
  float sc = xv.x * sKq[2*lane] + xv.y * sKq[2*lane + 1];

  for (int off = 32; off; off >>= 1) {
    deg += __shfl_xor(deg, off);
    e2c += __shfl_xor(e2c, off);
    sc  += __shfl_xor(sc, off);
  }
  if (lane == 0) {
    float dd = fmaxf(deg, 1.0f);
    cand_ws[grow] = sc * 0.125f + 0.2f * (e2c / dd);  // /sqrt(64) == *0.125
  }
}

// ---- Kernel C: theta MLP + sigmoid gate + count/top-2/trim, 1 block/batch ---
__global__ __launch_bounds__(1024) void finish_kernel(
    const float* __restrict__ seed_ctx, const float* __restrict__ local_stats,
    const float* __restrict__ candm,
    const float* __restrict__ W1, const float* __restrict__ b1,
    const float* __restrict__ W2, const float* __restrict__ b2,
    const float* __restrict__ cand_ws,
    float* __restrict__ out_hard, float* __restrict__ out_p,
    float* __restrict__ out_theta)
{
  const int b = blockIdx.x;
  const int t = threadIdx.x;

  __shared__ float tin[TH_IN];
  __shared__ float part[8][TH_HID];
  __shared__ float sred[TH_HID];
  __shared__ float s_theta;

  // ---- theta = Linear(387->128) -> ReLU -> Linear(128->1) ----
  if (t < ND + NHID) tin[t] = seed_ctx[b*(ND+NHID) + t];
  if (t >= ND + NHID && t < TH_IN) tin[t] = local_stats[b*3 + (t - (ND+NHID))];
  __syncthreads();
  {
    const int c = t >> 7;            // i-chunk 0..7 (~49 each)
    const int h = t & 127;
    const int i0 = c*49;
    const int i1 = (c == 7) ? TH_IN : i0 + 49;
    float acc = 0.f;
    for (int i = i0; i < i1; ++i) acc += tin[i] * W1[i*TH_HID + h];
    part[c][h] = acc;
  }
  __syncthreads();
  if (t < TH_HID) {
    float acc = b1[t];
    #pragma unroll
    for (int c = 0; c < 8; ++c) acc += part[c][t];
    acc = fmaxf(acc, 0.f);
    sred[t] = acc * W2[t];
  }
  __syncthreads();
  if (t < 64) {
    float v = sred[t] + sred[t + 64];
    for (int off = 32; off; off >>= 1) v += __shfl_xor(v, off);
    if (t == 0) {
      s_theta = v + b2[0];
      out_theta[b] = s_theta;
    }
  }
  __syncthreads();
  const float theta = s_theta;

  // ---- p = sigmoid(cand - theta) * cand_mask; local count/top-2 (2 elems) --
  float* p    = out_p    + b*NN;
  float* hard = out_hard + b*NN;

  __shared__ int scnt[1024];
  __shared__ float sv1[1024]; __shared__ int si1[1024];
  __shared__ float sv2[1024]; __shared__ int si2[1024];
  __shared__ int s_trim, s_k1, s_k2;

  int cnt = 0;
  float v1 = -1e30f, v2 = -1e30f; int i1 = 0, i2 = 0;
  #pragma unroll
  for (int j = 0; j < 2; ++j) {
    const int nidx = t*2 + j;                 // ascending within thread
    float cand = cand_ws[b*NN + nidx];
    float pv = 1.0f / (1.0f + expf(-(cand - theta)));
    pv *= candm[b*NN + nidx];
    p[nidx] = pv;
    hard[nidx] = (pv > 0.5f) ? 1.0f : 0.0f;
    if (pv > 0.5f) ++cnt;
    if (pv > v1)      { v2 = v1; i2 = i1; v1 = pv; i1 = nidx; }
    else if (pv > v2) { v2 = pv; i2 = nidx; }
  }
  scnt[t] = cnt; sv1[t]=v1; si1[t]=i1; sv2[t]=v2; si2[t]=i2;
  __syncthreads();
  // tree-merge: thread t covers strictly lower indices than t+s; strict '>'
  // preserves lax.top_k's lowest-index tie-break.
  for (int s = 512; s > 0; s >>= 1) {
    if (t < s) {
      scnt[t] += scnt[t+s];
      float B1 = sv1[t+s]; int Bi1 = si1[t+s];
      float B2 = sv2[t+s]; int Bi2 = si2[t+s];
      float V1 = sv1[t], V2 = sv2[t]; int I1 = si1[t], I2 = si2[t];
      if (B1 > V1)      { V2=V1; I2=I1; V1=B1; I1=Bi1; }
      else if (B1 > V2) { V2=B1; I2=Bi1; }
      if (B2 > V1)      { V2=V1; I2=I1; V1=B2; I1=Bi2; }
      else if (B2 > V2) { V2=B2; I2=Bi2; }
      sv1[t]=V1; si1[t]=I1; sv2[t]=V2; si2[t]=I2;
    }
    __syncthreads();
  }
  if (t == 0) {
    s_trim = (scnt[0] > 2) ? 1 : 0;   // over = count - (CLUSTER_SIZE_MAX-1) > 0
    s_k1 = si1[0]; s_k2 = si2[0];
  }
  __syncthreads();
  if (s_trim) {
    #pragma unroll
    for (int j = 0; j < 2; ++j) {
      const int nidx = t*2 + j;
      if (nidx != s_k1 && nidx != s_k2) { p[nidx] = 0.f; hard[nidx] = 0.f; }
    }
  }
}

extern "C" void kernel_launch(void* const* d_in, const int* in_sizes, int n_in,
                              void* d_out, int out_size, void* d_ws, size_t ws_size,
                              hipStream_t stream) {
  const float* x          = (const float*)d_in[0];
  const float* adj        = (const float*)d_in[1];
  const float* seed_ctx   = (const float*)d_in[2];
  const float* local_st   = (const float*)d_in[3];
  const float* cmask      = (const float*)d_in[4];
  const float* candm      = (const float*)d_in[5];
  const float* Wq         = (const float*)d_in[6];
  const float* Wk         = (const float*)d_in[7];
  const float* W1         = (const float*)d_in[8];
  const float* b1         = (const float*)d_in[9];
  const float* W2         = (const float*)d_in[10];
  const float* b2         = (const float*)d_in[11];

  float* out      = (float*)d_out;
  float* out_hard = out;                // [B,N]
  float* out_p    = out + NB*NN;        // [B,N]
  float* out_th   = out + 2*NB*NN;      // [B]

  float* cand_ws  = (float*)d_ws;       // B*N floats, fully rewritten each call

  row_cand_kernel<<<NB*NN/8, 512, 0, stream>>>(x, adj, cmask, Wq, Wk, cand_ws);
  finish_kernel<<<NB, 1024, 0, stream>>>(seed_ctx, local_st, candm,
                                         W1, b1, W2, b2, cand_ws,
                                         out_hard, out_p, out_th);
}